// Round 8
// baseline (147.896 us; speedup 1.0000x reference)
//
#include <hip/hip_runtime.h>
#include <hip/hip_bf16.h>

static constexpr int NN  = 50000;  // nodes
static constexpr int KNB = 32;     // neighbors
static constexpr int F   = 128;    // features
static constexpr int E   = 8;      // edge features
static constexpr int TI  = 16;     // nodes per block (3125 blocks)
static constexpr int LN  = F * E;  // 1024 contraction length

typedef __attribute__((ext_vector_type(8))) short short8v;
typedef __attribute__((ext_vector_type(4))) float f32x4;

__device__ __forceinline__ unsigned short f2bf(float x) {
    unsigned u = __float_as_uint(x);
    unsigned r = (u + 0x7fff + ((u >> 16) & 1)) >> 16;   // RNE
    return (unsigned short)r;
}
__device__ __forceinline__ float bf2f(unsigned short b) {
    return __uint_as_float(((unsigned)b) << 16);
}

// ---------- prep A: w[l,m,n] -> W2f bf16 in B-fragment order ----------
// W2f[((kb*128 + m)*4 + kq)*8 + e8] = bf16( w[l,m,n] ) where
//   k = kb*32 + kq*4 + (e8&3) + (e8>>2)*16 ,  l = k>>3, n = k&7
__global__ void prep_w_kernel(const float* __restrict__ w, unsigned short* __restrict__ w2f) {
    int o  = blockIdx.x * 256 + threadIdx.x;          // 131072 total
    int e8 = o & 7, kq = (o >> 3) & 3, m = (o >> 5) & 127, kb = o >> 12;
    int k  = kb * 32 + kq * 4 + (e8 & 3) + ((e8 >> 2) << 4);
    int l  = k >> 3, n = k & 7;
    w2f[o] = f2bf(w[(size_t)(l * F + m) * E + n]);
}

// ---------- prep B: nodes fp32 -> bf16 (3125 blocks x 256 thr x 8 elems = exact) ----------
__global__ void prep_nodes_kernel(const float* __restrict__ nodes, unsigned short* __restrict__ nb) {
    int t = blockIdx.x * 256 + threadIdx.x;
    const float4* s = (const float4*)nodes + (size_t)t * 2;
    float4 a = s[0], b = s[1];
    uint4 pk;
    pk.x = (unsigned)f2bf(a.x) | ((unsigned)f2bf(a.y) << 16);
    pk.y = (unsigned)f2bf(a.z) | ((unsigned)f2bf(a.w) << 16);
    pk.z = (unsigned)f2bf(b.x) | ((unsigned)f2bf(b.y) << 16);
    pk.w = (unsigned)f2bf(b.z) | ((unsigned)f2bf(b.w) << 16);
    ((uint4*)nb)[t] = pk;
}

// ---------- main fused kernel ----------
// stage 1 (MFMA): per node i, T[l][n] = sum_j Ng[j][l] * E[j][n] as ONE
//   mfma_16x16x32 per l-tile: A = E^T (16n x 32j, rows n>=8 zero),
//   B = Ng (32j x 16l) read from transposed LDS ngT[128l][34j-padded].
//   Block-cooperative, double-buffered: 8 waves stage 4 rows each (coalesced
//   4B/lane gather -> 2 x b16 transposed LDS writes), wave (k&7) also stages
//   the E A-fragment. One barrier per node.
// stage 2 (MFMA): out[i][m] = inv[i] * sum_ln T[i][ln] * W2[ln][m]  (as R7)
template<bool NB>
__global__ __launch_bounds__(512, 6)
void mp_main_kernel(const float* __restrict__ nodes,
                    const unsigned short* __restrict__ nodesBf,
                    const int*   __restrict__ nlist,
                    const float* __restrict__ edges,
                    const float* __restrict__ inv_degree,
                    const unsigned short* __restrict__ w2f,
                    float* __restrict__ out)
{
    __shared__ unsigned short tS[TI * LN];                    // 32 KiB; 16B-slot XOR swizzle by row
    __shared__ __align__(16) unsigned short ngT[2][128 * 34]; // 2 x 8704 B (rows l, 34-entry pitch)
    __shared__ __align__(16) unsigned short afS[2][512];      // 2 x 1 KiB (E A-fragment per node)
    const int tid    = threadIdx.x;
    const int wv     = __builtin_amdgcn_readfirstlane(tid >> 6);   // wave id 0..7
    const int lane   = tid & 63;
    const int cl     = lane & 15;
    const int kq     = lane >> 4;
    const int i_base = blockIdx.x * TI;
    char* tB = (char*)tS;

    if (NB) {
        // -------- stage 1: MFMA over nodes, double-buffered --------
        // STAGE(k): gather node k's 32 neighbor rows into ngT[k&1] (transposed),
        //           wave (k&7) builds E A-frag into afS[k&1].
        // COMPUTE(k): one MFMA per wave (l-tile = wv), D -> tS.
        auto stage = [&](int k) {
            const int b  = k & 1;
            const int gi = i_base + k;
            const int* nl = nlist + (size_t)gi * KNB;
            unsigned pvs[4];
            #pragma unroll
            for (int jj = 0; jj < 4; ++jj) {
                unsigned idx = (unsigned)nl[wv * 4 + jj];     // wave-uniform -> s_load
                if (idx >= (unsigned)NN) idx = 0u;
                pvs[jj] = ((const unsigned*)(nodesBf + (size_t)idx * F))[lane]; // 4B/lane, 256B/row
            }
            #pragma unroll
            for (int jj = 0; jj < 4; ++jj) {
                const int j = wv * 4 + jj;
                ngT[b][(2 * lane) * 34 + j]     = (unsigned short)pvs[jj];        // Ng[j][2*lane]
                ngT[b][(2 * lane + 1) * 34 + j] = (unsigned short)(pvs[jj] >> 16);// Ng[j][2*lane+1]
            }
            if (wv == (k & 7)) {
                // A-frag: A[r=n][k] = E[j][n], n = cl (zero for n>=8), k-map as B-frags
                unsigned fr[4] = {0u, 0u, 0u, 0u};
                #pragma unroll
                for (int e = 0; e < 8; ++e) {
                    const int j = kq * 4 + (e & 3) + ((e >> 2) << 4);
                    float v = 0.f;
                    if (cl < 8) v = edges[(size_t)gi * (KNB * E) + j * E + cl];
                    fr[e >> 1] |= (unsigned)f2bf(v) << ((e & 1) * 16);
                }
                *(uint4*)(&afS[b][lane * 8]) = make_uint4(fr[0], fr[1], fr[2], fr[3]);
            }
        };
        auto compute = [&](int k) {
            const int b = k & 1;
            union { short8v v; uint4 u; } ea;
            ea.u = *(const uint4*)(&afS[b][lane * 8]);
            const char* ngB = (const char*)&ngT[b][0];
            const int rowb = (wv * 16 + cl) * 68;             // l-row byte base (pitch 68B)
            union { short8v v; unsigned u[4]; } bb;           // B[k][c=l]: j = kq*4+{0..3}, 16+kq*4+{0..3}
            bb.u[0] = *(const unsigned*)(ngB + rowb + kq * 8);
            bb.u[1] = *(const unsigned*)(ngB + rowb + kq * 8 + 4);
            bb.u[2] = *(const unsigned*)(ngB + rowb + 32 + kq * 8);
            bb.u[3] = *(const unsigned*)(ngB + rowb + 32 + kq * 8 + 4);
            f32x4 d = {0.f, 0.f, 0.f, 0.f};
            d = __builtin_amdgcn_mfma_f32_16x16x32_bf16(ea.v, bb.v, d, 0, 0, 0);
            // D: col(lane&15)=l, row(kq*4+r)=n; valid n<8 -> kq<2. ln = l*8+n.
            if (kq < 2) {
                const unsigned d0 = (unsigned)f2bf(d[0]) | ((unsigned)f2bf(d[1]) << 16);
                const unsigned d1 = (unsigned)f2bf(d[2]) | ((unsigned)f2bf(d[3]) << 16);
                const int lg = wv * 16 + cl;
                const int bp = lg * 16 + kq * 8;              // = 2*ln(r=0)
                *(uint2*)(tB + k * (LN * 2) + (bp ^ ((k & 7) << 4))) = make_uint2(d0, d1);
            }
        };
        stage(0);
        __syncthreads();
        for (int k = 0; k < TI; ++k) {
            if (k < TI - 1) stage(k + 1);
            compute(k);
            __syncthreads();
        }
    } else {
        // fallback: direct fp32 gathers + VALU FMA (2 rows per wave), as R7
        for (int it = 0; it < 2; ++it) {
            const int row = wv * 2 + it;
            const int i   = i_base + row;
            const int*   nl = nlist + (size_t)i * KNB;
            const float* ep = edges + (size_t)i * (KNB * E);
            float a0[E], a1[E];
            #pragma unroll
            for (int n = 0; n < E; ++n) { a0[n] = 0.f; a1[n] = 0.f; }
            #pragma unroll 4
            for (int j = 0; j < KNB; ++j) {
                unsigned idx = (unsigned)nl[j];
                if (idx >= (unsigned)NN) idx = 0u;
                const float2 fv = ((const float2*)(nodes + (size_t)idx * F))[lane];
                const float4 e0 = *(const float4*)(ep + j * 8);
                const float4 e1 = *(const float4*)(ep + j * 8 + 4);
                a0[0] = __builtin_fmaf(e0.x, fv.x, a0[0]); a1[0] = __builtin_fmaf(e0.x, fv.y, a1[0]);
                a0[1] = __builtin_fmaf(e0.y, fv.x, a0[1]); a1[1] = __builtin_fmaf(e0.y, fv.y, a1[1]);
                a0[2] = __builtin_fmaf(e0.z, fv.x, a0[2]); a1[2] = __builtin_fmaf(e0.z, fv.y, a1[2]);
                a0[3] = __builtin_fmaf(e0.w, fv.x, a0[3]); a1[3] = __builtin_fmaf(e0.w, fv.y, a1[3]);
                a0[4] = __builtin_fmaf(e1.x, fv.x, a0[4]); a1[4] = __builtin_fmaf(e1.x, fv.y, a1[4]);
                a0[5] = __builtin_fmaf(e1.y, fv.x, a0[5]); a1[5] = __builtin_fmaf(e1.y, fv.y, a1[5]);
                a0[6] = __builtin_fmaf(e1.z, fv.x, a0[6]); a1[6] = __builtin_fmaf(e1.z, fv.y, a1[6]);
                a0[7] = __builtin_fmaf(e1.w, fv.x, a0[7]); a1[7] = __builtin_fmaf(e1.w, fv.y, a1[7]);
            }
            uint4 pk0, pk1;
            pk0.x = (unsigned)f2bf(a0[0]) | ((unsigned)f2bf(a0[1]) << 16);
            pk0.y = (unsigned)f2bf(a0[2]) | ((unsigned)f2bf(a0[3]) << 16);
            pk0.z = (unsigned)f2bf(a0[4]) | ((unsigned)f2bf(a0[5]) << 16);
            pk0.w = (unsigned)f2bf(a0[6]) | ((unsigned)f2bf(a0[7]) << 16);
            pk1.x = (unsigned)f2bf(a1[0]) | ((unsigned)f2bf(a1[1]) << 16);
            pk1.y = (unsigned)f2bf(a1[2]) | ((unsigned)f2bf(a1[3]) << 16);
            pk1.z = (unsigned)f2bf(a1[4]) | ((unsigned)f2bf(a1[5]) << 16);
            pk1.w = (unsigned)f2bf(a1[6]) | ((unsigned)f2bf(a1[7]) << 16);
            const int s  = (row & 7) << 4;
            const int rb = row * (LN * 2);
            *(uint4*)(tB + rb + ((lane * 32)      ^ s)) = pk0;
            *(uint4*)(tB + rb + ((lane * 32 + 16) ^ s)) = pk1;
        }
        __syncthreads();
    }

    // ---------------- stage 2: MFMA, one 16x16 m-tile per wave ----------------
    const int mt = wv;                                // m-tile 0..7

    f32x4 c0 = {0.f, 0.f, 0.f, 0.f};

    const int arow = cl * (LN * 2);
    const int asw  = (cl & 7) << 4;

    #pragma unroll 4
    for (int kb = 0; kb < LN / 32; ++kb) {
        union { short8v v; uint2 u[2]; } af;
        af.u[0] = *(const uint2*)(tB + arow + ((kb * 64      + kq * 8) ^ asw)); // k=kb*32+kq*4+e
        af.u[1] = *(const uint2*)(tB + arow + ((kb * 64 + 32 + kq * 8) ^ asw)); // k=kb*32+16+kq*4+e
        union { short8v v; uint4 u; } b0;
        b0.u = *(const uint4*)(w2f + ((size_t)((kb * 128 + mt * 16 + cl) * 4 + kq)) * 8);
        c0 = __builtin_amdgcn_mfma_f32_16x16x32_bf16(af.v, b0.v, c0, 0, 0, 0);
    }

    // C/D: col = lane&15, row = (lane>>4)*4 + r   [measured m89]
    #pragma unroll
    for (int r = 0; r < 4; ++r) {
        const int ii = kq * 4 + r;
        const int gi = i_base + ii;
        out[(size_t)gi * F + mt * 16 + cl] = inv_degree[gi] * c0[r];
    }
}

// ---------- fallback (round-1 kernel, pure fp32) for tiny ws ----------
__global__ __launch_bounds__(256, 2)
void mp_fused_fallback(const float* __restrict__ nodes, const int* __restrict__ nlist,
                       const float* __restrict__ edges, const float* __restrict__ inv_degree,
                       const float* __restrict__ w, float* __restrict__ out)
{
    __shared__ float tLds[TI * F * E];
    const int tid = threadIdx.x;
    const int i_base = blockIdx.x * TI;
    {
        const int l = tid & (F - 1);
        const int half = __builtin_amdgcn_readfirstlane(tid >> 7);
        for (int g = 0; g < TI / 2; ++g) {
            const int ii = g * 2 + half;
            const int i = i_base + ii;
            float acc[E];
            #pragma unroll
            for (int n = 0; n < E; ++n) acc[n] = 0.f;
            const int* nl = nlist + i * KNB;
            const float* ep = edges + (size_t)i * (KNB * E);
            #pragma unroll 4
            for (int j = 0; j < KNB; ++j) {
                unsigned idx = (unsigned)nl[j];
                if (idx >= (unsigned)NN) idx = 0u;
                const float v = nodes[idx * F + l];
                #pragma unroll
                for (int n = 0; n < E; ++n) acc[n] = __builtin_fmaf(ep[j * E + n], v, acc[n]);
            }
            float4* dst = (float4*)&tLds[ii * (F * E) + l * E];
            dst[0] = make_float4(acc[0], acc[1], acc[2], acc[3]);
            dst[1] = make_float4(acc[4], acc[5], acc[6], acc[7]);
        }
    }
    __syncthreads();
    const int m_lo = tid & 63;
    const int q = __builtin_amdgcn_readfirstlane(tid >> 6);
    float accA[TI], accB[TI];
    #pragma unroll
    for (int ii = 0; ii < TI; ++ii) { accA[ii] = 0.f; accB[ii] = 0.f; }
    for (int lq = 0; lq < F / 4; ++lq) {
        const int l = q * (F / 4) + lq;
        const float4* wp0 = (const float4*)&w[(size_t)l * (F * E) + (size_t)m_lo * E];
        const float4* wp1 = (const float4*)&w[(size_t)l * (F * E) + (size_t)(m_lo + 64) * E];
        const float4 w0a = wp0[0], w0b = wp0[1];
        const float4 w1a = wp1[0], w1b = wp1[1];
        #pragma unroll
        for (int ii = 0; ii < TI; ++ii) {
            const float4* tp = (const float4*)&tLds[ii * (F * E) + l * E];
            const float4 ta = tp[0], tb = tp[1];
            float sA = accA[ii], sB = accB[ii];
            sA = __builtin_fmaf(ta.x, w0a.x, sA); sA = __builtin_fmaf(ta.y, w0a.y, sA);
            sA = __builtin_fmaf(ta.z, w0a.z, sA); sA = __builtin_fmaf(ta.w, w0a.w, sA);
            sA = __builtin_fmaf(tb.x, w0b.x, sA); sA = __builtin_fmaf(tb.y, w0b.y, sA);
            sA = __builtin_fmaf(tb.z, w0b.z, sA); sA = __builtin_fmaf(tb.w, w0b.w, sA);
            sB = __builtin_fmaf(ta.x, w1a.x, sB); sB = __builtin_fmaf(ta.y, w1a.y, sB);
            sB = __builtin_fmaf(ta.z, w1a.z, sB); sB = __builtin_fmaf(ta.w, w1a.w, sB);
            sB = __builtin_fmaf(tb.x, w1b.x, sB); sB = __builtin_fmaf(tb.y, w1b.y, sB);
            sB = __builtin_fmaf(tb.z, w1b.z, sB); sB = __builtin_fmaf(tb.w, w1b.w, sB);
            accA[ii] = sA; accB[ii] = sB;
        }
    }
    __syncthreads();
    float* pLds = tLds;
    #pragma unroll
    for (int ii = 0; ii < TI; ++ii) {
        pLds[q * (TI * F) + ii * F + m_lo] = accA[ii];
        pLds[q * (TI * F) + ii * F + m_lo + 64] = accB[ii];
    }
    __syncthreads();
    #pragma unroll
    for (int r = 0; r < (TI * F) / 256; ++r) {
        const int o = r * 256 + tid;
        const int ii = o >> 7;
        const int m = o & (F - 1);
        const float s = pLds[0 * (TI * F) + ii * F + m] + pLds[1 * (TI * F) + ii * F + m]
                      + pLds[2 * (TI * F) + ii * F + m] + pLds[3 * (TI * F) + ii * F + m];
        const int i = i_base + ii;
        out[(size_t)i * F + m] = inv_degree[i] * s;
    }
}

extern "C" void kernel_launch(void* const* d_in, const int* in_sizes, int n_in,
                              void* d_out, int out_size, void* d_ws, size_t ws_size,
                              hipStream_t stream) {
    const float* nodes      = (const float*)d_in[0];
    const int*   nlist      = (const int*)d_in[1];
    const float* edges      = (const float*)d_in[2];
    const float* inv_degree = (const float*)d_in[3];
    const float* w          = (const float*)d_in[4];
    float* out = (float*)d_out;
    (void)in_sizes; (void)n_in; (void)out_size;

    const size_t need_w2 = (size_t)LN * F * 2;                  // 256 KiB
    const size_t need_nb = (size_t)NN * F * 2;                  // 12.8 MiB

    if (ws_size < need_w2) {
        mp_fused_fallback<<<dim3(NN / TI), dim3(256), 0, stream>>>(
            nodes, nlist, edges, inv_degree, w, out);
        return;
    }
    unsigned short* w2f = (unsigned short*)d_ws;
    unsigned short* nb  = (unsigned short*)((char*)d_ws + need_w2);

    prep_w_kernel<<<dim3((LN * F) / 256), dim3(256), 0, stream>>>(w, w2f);
    if (ws_size >= need_w2 + need_nb) {
        prep_nodes_kernel<<<dim3(NN * F / 8 / 256), dim3(256), 0, stream>>>(nodes, nb);
        mp_main_kernel<true><<<dim3(NN / TI), dim3(512), 0, stream>>>(
            nodes, nb, nlist, edges, inv_degree, w2f, out);
    } else {
        mp_main_kernel<false><<<dim3(NN / TI), dim3(512), 0, stream>>>(
            nodes, nb, nlist, edges, inv_degree, w2f, out);
    }
}

// Round 9
// 101.333 us; speedup vs baseline: 1.4595x; 1.4595x over previous
//
#include <hip/hip_runtime.h>
#include <hip/hip_bf16.h>

static constexpr int NN  = 50000;  // nodes
static constexpr int KNB = 32;     // neighbors
static constexpr int F   = 128;    // features
static constexpr int E   = 8;      // edge features
static constexpr int TI  = 16;     // nodes per block (3125 blocks)
static constexpr int LN  = F * E;  // 1024 contraction length

typedef __attribute__((ext_vector_type(8))) short short8v;
typedef __attribute__((ext_vector_type(4))) float f32x4;

__device__ __forceinline__ unsigned short f2bf(float x) {
    unsigned u = __float_as_uint(x);
    unsigned r = (u + 0x7fff + ((u >> 16) & 1)) >> 16;   // RNE
    return (unsigned short)r;
}

// ---------- prep A: w[l,m,n] -> W2f bf16 in B-fragment order ----------
// W2f[((kb*128 + m)*4 + kq)*8 + e8] = bf16( w[l,m,n] ) where
//   k = kb*32 + kq*4 + (e8&3) + (e8>>2)*16 ,  l = k>>3, n = k&7
__global__ void prep_w_kernel(const float* __restrict__ w, unsigned short* __restrict__ w2f) {
    int o  = blockIdx.x * 256 + threadIdx.x;          // 131072 total
    int e8 = o & 7, kq = (o >> 3) & 3, m = (o >> 5) & 127, kb = o >> 12;
    int k  = kb * 32 + kq * 4 + (e8 & 3) + ((e8 >> 2) << 4);
    int l  = k >> 3, n = k & 7;
    w2f[o] = f2bf(w[(size_t)(l * F + m) * E + n]);
}

// ---------- prep B: nodes fp32 -> bf16 (3125 blocks x 256 thr x 8 elems = exact) ----------
__global__ void prep_nodes_kernel(const float* __restrict__ nodes, unsigned short* __restrict__ nb) {
    int t = blockIdx.x * 256 + threadIdx.x;
    const float4* s = (const float4*)nodes + (size_t)t * 2;
    float4 a = s[0], b = s[1];
    uint4 pk;
    pk.x = (unsigned)f2bf(a.x) | ((unsigned)f2bf(a.y) << 16);
    pk.y = (unsigned)f2bf(a.z) | ((unsigned)f2bf(a.w) << 16);
    pk.z = (unsigned)f2bf(b.x) | ((unsigned)f2bf(b.y) << 16);
    pk.w = (unsigned)f2bf(b.z) | ((unsigned)f2bf(b.w) << 16);
    ((uint4*)nb)[t] = pk;
}

// ---------- main fused kernel ----------
// R7 structure (512 thr / 8 waves, 32 KiB LDS, 4 blocks/CU) with stage-1 math
// on the packed-fp32 pipe: acc (a[2q],a[2q+1]) += (e[2q],e[2q+1]) * (v,v) via
// v_pk_fma_f32 (e-pair straight from SGPRs), pack via v_cvt_pk_bf16_f32.
template<bool NB>
__global__ __launch_bounds__(512, 8)
void mp_main_kernel(const float* __restrict__ nodes,
                    const unsigned short* __restrict__ nodesBf,
                    const int*   __restrict__ nlist,
                    const float* __restrict__ edges,
                    const float* __restrict__ inv_degree,
                    const unsigned short* __restrict__ w2f,
                    float* __restrict__ out)
{
    __shared__ unsigned short tS[TI * LN];            // 32 KiB; 16B-slot XOR swizzle by row
    const int tid    = threadIdx.x;
    const int wv     = __builtin_amdgcn_readfirstlane(tid >> 6);   // wave id 0..7
    const int lane   = tid & 63;
    const int i_base = blockIdx.x * TI;
    char* tB = (char*)tS;

    // ---------------- stage 1: 2 rows per wave ----------------
    for (int it = 0; it < 2; ++it) {
        const int row = wv * 2 + it;                  // uniform 0..15
        const int i   = i_base + row;
        const int*   nl = nlist + (size_t)i * KNB;
        const float* ep = edges + (size_t)i * (KNB * E);

        // acc pairs: p0[q] = (a[2q], a[2q+1]) for column v0; p1[q] for column v1
        float2 p0[4], p1[4];
        #pragma unroll
        for (int q = 0; q < 4; ++q) { p0[q] = make_float2(0.f, 0.f); p1[q] = make_float2(0.f, 0.f); }

        #pragma unroll
        for (int j = 0; j < KNB; ++j) {
            unsigned idx = (unsigned)nl[j];
            if (idx >= (unsigned)NN) idx = 0u;
            idx = __builtin_amdgcn_readfirstlane(idx);           // scalar-pipe addressing
            unsigned g;
            if (NB) {
                g = ((const unsigned*)(nodesBf + (size_t)idx * F))[lane];  // 4B/lane gather
            } else {
                const float2 fv = ((const float2*)(nodes + (size_t)idx * F))[lane];
                g = ((unsigned)f2bf(fv.y) << 16) | (unsigned)f2bf(fv.x);
            }
            // uniform edge pairs (consecutive SGPRs after scalarization)
            const float2 e01 = *(const float2*)(ep + j * 8 + 0);
            const float2 e23 = *(const float2*)(ep + j * 8 + 2);
            const float2 e45 = *(const float2*)(ep + j * 8 + 4);
            const float2 e67 = *(const float2*)(ep + j * 8 + 6);
            // v broadcast pairs
            float2 vv0, vv1;
            vv0.x = __uint_as_float(g << 16);         vv0.y = vv0.x;
            vv1.x = __uint_as_float(g & 0xffff0000u); vv1.y = vv1.x;
            asm("v_pk_fma_f32 %0, %1, %2, %0" : "+v"(p0[0]) : "s"(e01), "v"(vv0));
            asm("v_pk_fma_f32 %0, %1, %2, %0" : "+v"(p0[1]) : "s"(e23), "v"(vv0));
            asm("v_pk_fma_f32 %0, %1, %2, %0" : "+v"(p0[2]) : "s"(e45), "v"(vv0));
            asm("v_pk_fma_f32 %0, %1, %2, %0" : "+v"(p0[3]) : "s"(e67), "v"(vv0));
            asm("v_pk_fma_f32 %0, %1, %2, %0" : "+v"(p1[0]) : "s"(e01), "v"(vv1));
            asm("v_pk_fma_f32 %0, %1, %2, %0" : "+v"(p1[1]) : "s"(e23), "v"(vv1));
            asm("v_pk_fma_f32 %0, %1, %2, %0" : "+v"(p1[2]) : "s"(e45), "v"(vv1));
            asm("v_pk_fma_f32 %0, %1, %2, %0" : "+v"(p1[3]) : "s"(e67), "v"(vv1));
        }

        // pack 16 bf16 (ln = lane*16 + 0..15 of row) via HW cvt_pk, swizzled store
        uint4 pk0, pk1;
        asm("v_cvt_pk_bf16_f32 %0, %1, %2" : "=v"(pk0.x) : "v"(p0[0].x), "v"(p0[0].y));
        asm("v_cvt_pk_bf16_f32 %0, %1, %2" : "=v"(pk0.y) : "v"(p0[1].x), "v"(p0[1].y));
        asm("v_cvt_pk_bf16_f32 %0, %1, %2" : "=v"(pk0.z) : "v"(p0[2].x), "v"(p0[2].y));
        asm("v_cvt_pk_bf16_f32 %0, %1, %2" : "=v"(pk0.w) : "v"(p0[3].x), "v"(p0[3].y));
        asm("v_cvt_pk_bf16_f32 %0, %1, %2" : "=v"(pk1.x) : "v"(p1[0].x), "v"(p1[0].y));
        asm("v_cvt_pk_bf16_f32 %0, %1, %2" : "=v"(pk1.y) : "v"(p1[1].x), "v"(p1[1].y));
        asm("v_cvt_pk_bf16_f32 %0, %1, %2" : "=v"(pk1.z) : "v"(p1[2].x), "v"(p1[2].y));
        asm("v_cvt_pk_bf16_f32 %0, %1, %2" : "=v"(pk1.w) : "v"(p1[3].x), "v"(p1[3].y));

        const int p2 = (lane >> 2) & 1;
        const int s  = (row & 7) << 4;
        const int rb = row * (LN * 2);
        const uint4 first  = p2 ? pk1 : pk0;
        const uint4 second = p2 ? pk0 : pk1;
        *(uint4*)(tB + rb + ((lane * 32 + (p2 << 4))      ^ s)) = first;
        *(uint4*)(tB + rb + ((lane * 32 + 16 - (p2 << 4)) ^ s)) = second;
    }
    __syncthreads();

    // ---------------- stage 2: MFMA, one 16x16 m-tile per wave ----------------
    const int colm = lane & 15;                       // i-row for A, m-col for B/C
    const int kq   = lane >> 4;
    const int mt   = wv;                              // m-tile 0..7

    f32x4 c0 = {0.f, 0.f, 0.f, 0.f};

    const int arow = colm * (LN * 2);
    const int asw  = (colm & 7) << 4;

    #pragma unroll 4
    for (int kb = 0; kb < LN / 32; ++kb) {
        union { short8v v; uint2 u[2]; } af;
        af.u[0] = *(const uint2*)(tB + arow + ((kb * 64      + kq * 8) ^ asw)); // k=kb*32+kq*4+e
        af.u[1] = *(const uint2*)(tB + arow + ((kb * 64 + 32 + kq * 8) ^ asw)); // k=kb*32+16+kq*4+e
        union { short8v v; uint4 u; } b0;
        b0.u = *(const uint4*)(w2f + ((size_t)((kb * 128 + mt * 16 + colm) * 4 + kq)) * 8);
        c0 = __builtin_amdgcn_mfma_f32_16x16x32_bf16(af.v, b0.v, c0, 0, 0, 0);
    }

    // C/D: col = lane&15, row = (lane>>4)*4 + r   [measured m89]
    #pragma unroll
    for (int r = 0; r < 4; ++r) {
        const int ii = kq * 4 + r;
        const int gi = i_base + ii;
        out[(size_t)gi * F + mt * 16 + colm] = inv_degree[gi] * c0[r];
    }
}

// ---------- fallback (round-1 kernel, pure fp32) for tiny ws ----------
__global__ __launch_bounds__(256, 2)
void mp_fused_fallback(const float* __restrict__ nodes, const int* __restrict__ nlist,
                       const float* __restrict__ edges, const float* __restrict__ inv_degree,
                       const float* __restrict__ w, float* __restrict__ out)
{
    __shared__ float tLds[TI * F * E];
    const int tid = threadIdx.x;
    const int i_base = blockIdx.x * TI;
    {
        const int l = tid & (F - 1);
        const int half = __builtin_amdgcn_readfirstlane(tid >> 7);
        for (int g = 0; g < TI / 2; ++g) {
            const int ii = g * 2 + half;
            const int i = i_base + ii;
            float acc[E];
            #pragma unroll
            for (int n = 0; n < E; ++n) acc[n] = 0.f;
            const int* nl = nlist + i * KNB;
            const float* ep = edges + (size_t)i * (KNB * E);
            #pragma unroll 4
            for (int j = 0; j < KNB; ++j) {
                unsigned idx = (unsigned)nl[j];
                if (idx >= (unsigned)NN) idx = 0u;
                const float v = nodes[idx * F + l];
                #pragma unroll
                for (int n = 0; n < E; ++n) acc[n] = __builtin_fmaf(ep[j * E + n], v, acc[n]);
            }
            float4* dst = (float4*)&tLds[ii * (F * E) + l * E];
            dst[0] = make_float4(acc[0], acc[1], acc[2], acc[3]);
            dst[1] = make_float4(acc[4], acc[5], acc[6], acc[7]);
        }
    }
    __syncthreads();
    const int m_lo = tid & 63;
    const int q = __builtin_amdgcn_readfirstlane(tid >> 6);
    float accA[TI], accB[TI];
    #pragma unroll
    for (int ii = 0; ii < TI; ++ii) { accA[ii] = 0.f; accB[ii] = 0.f; }
    for (int lq = 0; lq < F / 4; ++lq) {
        const int l = q * (F / 4) + lq;
        const float4* wp0 = (const float4*)&w[(size_t)l * (F * E) + (size_t)m_lo * E];
        const float4* wp1 = (const float4*)&w[(size_t)l * (F * E) + (size_t)(m_lo + 64) * E];
        const float4 w0a = wp0[0], w0b = wp0[1];
        const float4 w1a = wp1[0], w1b = wp1[1];
        #pragma unroll
        for (int ii = 0; ii < TI; ++ii) {
            const float4* tp = (const float4*)&tLds[ii * (F * E) + l * E];
            const float4 ta = tp[0], tb = tp[1];
            float sA = accA[ii], sB = accB[ii];
            sA = __builtin_fmaf(ta.x, w0a.x, sA); sA = __builtin_fmaf(ta.y, w0a.y, sA);
            sA = __builtin_fmaf(ta.z, w0a.z, sA); sA = __builtin_fmaf(ta.w, w0a.w, sA);
            sA = __builtin_fmaf(tb.x, w0b.x, sA); sA = __builtin_fmaf(tb.y, w0b.y, sA);
            sA = __builtin_fmaf(tb.z, w0b.z, sA); sA = __builtin_fmaf(tb.w, w0b.w, sA);
            sB = __builtin_fmaf(ta.x, w1a.x, sB); sB = __builtin_fmaf(ta.y, w1a.y, sB);
            sB = __builtin_fmaf(ta.z, w1a.z, sB); sB = __builtin_fmaf(ta.w, w1a.w, sB);
            sB = __builtin_fmaf(tb.x, w1b.x, sB); sB = __builtin_fmaf(tb.y, w1b.y, sB);
            sB = __builtin_fmaf(tb.z, w1b.z, sB); sB = __builtin_fmaf(tb.w, w1b.w, sB);
            accA[ii] = sA; accB[ii] = sB;
        }
    }
    __syncthreads();
    float* pLds = tLds;
    #pragma unroll
    for (int ii = 0; ii < TI; ++ii) {
        pLds[q * (TI * F) + ii * F + m_lo] = accA[ii];
        pLds[q * (TI * F) + ii * F + m_lo + 64] = accB[ii];
    }
    __syncthreads();
    #pragma unroll
    for (int r = 0; r < (TI * F) / 256; ++r) {
        const int o = r * 256 + tid;
        const int ii = o >> 7;
        const int m = o & (F - 1);
        const float s = pLds[0 * (TI * F) + ii * F + m] + pLds[1 * (TI * F) + ii * F + m]
                      + pLds[2 * (TI * F) + ii * F + m] + pLds[3 * (TI * F) + ii * F + m];
        const int i = i_base + ii;
        out[(size_t)i * F + m] = inv_degree[i] * s;
    }
}

extern "C" void kernel_launch(void* const* d_in, const int* in_sizes, int n_in,
                              void* d_out, int out_size, void* d_ws, size_t ws_size,
                              hipStream_t stream) {
    const float* nodes      = (const float*)d_in[0];
    const int*   nlist      = (const int*)d_in[1];
    const float* edges      = (const float*)d_in[2];
    const float* inv_degree = (const float*)d_in[3];
    const float* w          = (const float*)d_in[4];
    float* out = (float*)d_out;
    (void)in_sizes; (void)n_in; (void)out_size;

    const size_t need_w2 = (size_t)LN * F * 2;                  // 256 KiB
    const size_t need_nb = (size_t)NN * F * 2;                  // 12.8 MiB

    if (ws_size < need_w2) {
        mp_fused_fallback<<<dim3(NN / TI), dim3(256), 0, stream>>>(
            nodes, nlist, edges, inv_degree, w, out);
        return;
    }
    unsigned short* w2f = (unsigned short*)d_ws;
    unsigned short* nb  = (unsigned short*)((char*)d_ws + need_w2);

    prep_w_kernel<<<dim3((LN * F) / 256), dim3(256), 0, stream>>>(w, w2f);
    if (ws_size >= need_w2 + need_nb) {
        prep_nodes_kernel<<<dim3(NN * F / 8 / 256), dim3(256), 0, stream>>>(nodes, nb);
        mp_main_kernel<true><<<dim3(NN / TI), dim3(512), 0, stream>>>(
            nodes, nb, nlist, edges, inv_degree, w2f, out);
    } else {
        mp_main_kernel<false><<<dim3(NN / TI), dim3(512), 0, stream>>>(
            nodes, nb, nlist, edges, inv_degree, w2f, out);
    }
}